// Round 17
// baseline (151.874 us; speedup 1.0000x reference)
//
#include <hip/hip_runtime.h>
#include <math.h>

// Problem constants: N=12000, NEI=32, K=8, D=64
#define NPTS 12000
#define NNEI 32
#define KK   8
#define DD   64

// Round 17 (= R12 performance structure + flake hardening):
//  - R16 ran the identical R12 code and failed ONLY the post-timing
//    revalidation (first check passed) -> suspected cross-kernel visibility
//    flake at graph-node boundaries (per-XCD L2s are not cross-coherent).
//  - Hardening: (1) __threadfence() device-scope release at the end of each
//    producer kernel; (2) kmF/esA handoff ELIMINATED -- passA recomputes the
//    km row + exp(scales) per block (measured ~free in R11); packW -> passA
//    dependency is now Wpk only.
//  - Performance structure unchanged from R12 (best proven 30.7us):
//    packW fragments, 750x512 balanced passA (fp32 dot -> exact u=1/z
//    softmax, split-bf16 MFMA, stride-68 xtr), coalesced passB.

typedef __bf16 bf16x8 __attribute__((ext_vector_type(8)));
typedef float  f32x4  __attribute__((ext_vector_type(4)));

#define MFMA16(A, B, C) __builtin_amdgcn_mfma_f32_16x16x32_bf16((A), (B), (C), 0, 0, 0)

__device__ __forceinline__ void pack8(float4 u, float4 v, bf16x8& h, bf16x8& l) {
    float a[8] = {u.x, u.y, u.z, u.w, v.x, v.y, v.z, v.w};
    #pragma unroll
    for (int i = 0; i < 8; ++i) {
        __bf16 hh = (__bf16)a[i];
        h[i] = hh;
        l[i] = (__bf16)(a[i] - (float)hh);
    }
}

__device__ __forceinline__ float dot4(float4 a, float4 b) {
    return a.x * b.x + a.y * b.y + a.z * b.z + a.w * b.w;
}

// ---------------------------------------------------------------- packW ----
// 8 blocks x 512: W -> split-bf16 fragments in fragment order.
__launch_bounds__(512)
__global__ void packW_kernel(const float* __restrict__ W,
                             bf16x8* __restrict__ Wpk) {
    const int t    = threadIdx.x;
    const int id   = blockIdx.x * 512 + t;   // 0..4095
    const int lane = id & 63;
    const int ks   = (id >> 6) & 1;
    const int nt   = (id >> 7) & 3;
    const int k    = id >> 9;
    const int c    = lane & 15;
    const int g    = lane >> 4;

    const float* wr = W + ((size_t)k * DD + nt * 16 + c) * DD + ks * 32 + g * 8;
    bf16x8 h, l;
    pack8(*(const float4*)wr, *(const float4*)(wr + 4), h, l);
    const size_t base = ((((size_t)k * 4 + nt) * 2 + ks) * 2) * 64 + lane;
    Wpk[base]      = h;   // hi plane
    Wpk[base + 64] = l;   // lo plane

    __threadfence();      // device-scope release: Wpk visible before node end
}

// ---------------------------------------------------------------- pass A ---
__launch_bounds__(512)
__global__ void passA_kernel(const float* __restrict__ x,
                             const float* __restrict__ kp,
                             const float* __restrict__ scales,
                             const bf16x8* __restrict__ Wpk,
                             const float* __restrict__ b,
                             float* __restrict__ F) {
    __shared__ float xtr[KK][16][68];   // stride 68: write/read both 2-way (free)
    __shared__ float kmL[KK][DD];       // per-wave km row (wave-private)
    __shared__ float disl[16][12];      // u = 1/z per (point, k)

    const int t    = threadIdx.x;
    const int k    = t >> 6;            // wave index == kernel index
    const int lane = t & 63;
    const int c    = lane & 15;
    const int g    = lane >> 4;
    const int pbase = blockIdx.x * 16;

    // ---- km row for this wave's k (recomputed per block; ~free, R11) ----
    {
        float spv = (lane == 0) ? 0.f : kp[k * DD + lane];   // kp[:,0]==0
        float ss = spv * spv;
        #pragma unroll
        for (int off = 32; off > 0; off >>= 1) ss += __shfl_xor(ss, off);
        float nrm = sqrtf(fmaxf(ss, 1e-8f));
        float e  = __expf(nrm);
        float ei = 1.0f / e;
        kmL[k][lane] = (lane == 0) ? 0.5f * (e + ei)
                                   : -(0.5f * (e - ei) / nrm) * spv;
    }
    const float es = __expf(scales[k]);

    // ---- prologue: coalesced Wpk fragment loads ----
    bf16x8 Wh[4][2], Wl[4][2];
    #pragma unroll
    for (int nt = 0; nt < 4; ++nt)
        #pragma unroll
        for (int ks = 0; ks < 2; ++ks) {
            const size_t base = ((((size_t)k * 4 + nt) * 2 + ks) * 2) * 64 + lane;
            Wh[nt][ks] = Wpk[base];
            Wl[nt][ks] = Wpk[base + 64];
        }
    float bnt[4];
    #pragma unroll
    for (int nt = 0; nt < 4; ++nt) bnt[nt] = b[k * DD + nt * 16 + c];

    // ---- x row chunks (16 floats, kept live for dot + pack) ----
    float4 u0, u1, u2, u3;
    {
        const float* xr = x + (size_t)(pbase + c) * DD + g * 8;
        u0 = *(const float4*)(xr +  0);
        u1 = *(const float4*)(xr +  4);
        u2 = *(const float4*)(xr + 32);
        u3 = *(const float4*)(xr + 36);
    }

    // ---- inner product <x_row, km_k>; softmax numerator u = 1/z (exact) ----
    {
        const float4* km4 = (const float4*)&kmL[k][0];
        float ip = dot4(u0, km4[g * 2 + 0]) + dot4(u1, km4[g * 2 + 1])
                 + dot4(u2, km4[g * 2 + 8]) + dot4(u3, km4[g * 2 + 9]);
        ip += __shfl_xor(ip, 16);
        ip += __shfl_xor(ip, 32);   // all 4 g-groups summed; lanes with same c agree
        if (g == 0) {
            float nc = fmaxf(ip, 1.0f + 1e-7f);
            // exp(-arccosh(nc)) = 1 / (nc + sqrt(nc^2 - 1))  -- exact
            disl[c][k] = 1.0f / (nc + sqrtf(nc * nc - 1.0f));
        }
    }

    // ---- A fragments ----
    bf16x8 Ah[2], Al[2];
    pack8(u0, u1, Ah[0], Al[0]);
    pack8(u2, u3, Ah[1], Al[1]);

    // ---- MFMAs: Y only (24) ----
    f32x4 accY[4];
    #pragma unroll
    for (int nt = 0; nt < 4; ++nt) accY[nt] = (f32x4){0.f, 0.f, 0.f, 0.f};
    #pragma unroll
    for (int ks = 0; ks < 2; ++ks)
        #pragma unroll
        for (int nt = 0; nt < 4; ++nt) {
            accY[nt] = MFMA16(Ah[ks], Wh[nt][ks], accY[nt]);
            accY[nt] = MFMA16(Ah[ks], Wl[nt][ks], accY[nt]);
            accY[nt] = MFMA16(Al[ks], Wh[nt][ks], accY[nt]);
        }

    // ---- epilogue: per-point stats (C layout: row p=g*4+rr, col o=nt*16+c) ----
    float yv[4][4], sall[4];
    #pragma unroll
    for (int rr = 0; rr < 4; ++rr) {
        float s = 0.f;
        #pragma unroll
        for (int nt = 0; nt < 4; ++nt) {
            float y = accY[nt][rr] + bnt[nt];
            yv[nt][rr] = y;
            s += y * y;
        }
        sall[rr] = s;
    }
    #pragma unroll
    for (int m = 1; m <= 8; m <<= 1)
        #pragma unroll
        for (int rr = 0; rr < 4; ++rr) sall[rr] += __shfl_xor(sall[rr], m);
    float y0[4];
    #pragma unroll
    for (int rr = 0; rr < 4; ++rr) y0[rr] = __shfl(yv[0][rr], lane & 48);

    #pragma unroll
    for (int rr = 0; rr < 4; ++rr) {
        const int p = g * 4 + rr;
        float nar2 = fmaxf(sall[rr] - y0[rr] * y0[rr], 1e-8f);
        float time = es / (1.0f + __expf(-y0[rr])) + 1.0001f;
        float s3   = sqrtf((time * time - 1.0f) / nar2);
        #pragma unroll
        for (int nt = 0; nt < 4; ++nt) {
            float v = yv[nt][rr] * s3;
            if (nt == 0 && c == 0) v = time;
            xtr[k][p][nt * 16 + c] = v;
        }
    }
    __syncthreads();

    // ---- combine: wave k handles points {2k, 2k+1} ----
    #pragma unroll
    for (int pi = 0; pi < 2; ++pi) {
        const int p = k * 2 + pi;
        float uk[KK];
        float sum = 0.f;
        #pragma unroll
        for (int q = 0; q < KK; ++q) { uk[q] = disl[p][q]; sum += uk[q]; }
        float inv = 1.0f / sum;
        float agg = 0.f;
        #pragma unroll
        for (int q = 0; q < KK; ++q) agg += uk[q] * inv * xtr[q][p][lane];

        float vv = (lane == 0) ? -agg * agg : agg * agg;
        #pragma unroll
        for (int m = 32; m > 0; m >>= 1) vv += __shfl_xor(vv, m);
        float den = sqrtf(fmaxf(fabsf(vv), 1e-8f));
        F[(size_t)(pbase + p) * DD + lane] = agg / den;
    }

    __threadfence();      // device-scope release: F visible before node end
}

// ---------------------------------------------------------------- pass B ---
__launch_bounds__(256)
__global__ void passB_kernel(const float* __restrict__ F,
                             const int* __restrict__ nei,
                             const int* __restrict__ mask,
                             float* __restrict__ out) {
    const int t    = threadIdx.x;
    const int wave = t >> 6;
    const int lane = t & 63;
    const int c    = lane & 15;   // col quad: o = 4c..4c+3
    const int g    = lane >> 4;   // m sub-index
    const int n    = blockIdx.x * 4 + wave;

    // one coalesced 256B fetch per wave: lanes 0..31 nei row, 32..63 mask row
    int vsrc;
    if (lane < 32) vsrc = nei[n * NNEI + lane];
    else           vsrc = mask[n * NNEI + (lane - 32)];

    const float4* F4 = (const float4*)F;
    float4 acc = {0.f, 0.f, 0.f, 0.f};
    #pragma unroll
    for (int mq = 0; mq < 8; ++mq) {
        int   m   = mq * 4 + g;
        int   j   = __shfl(vsrc, m);
        float wgt = (float)__shfl(vsrc, 32 + m) + 1e-4f;
        float4 v  = F4[(size_t)j * 16 + c];
        acc.x += wgt * v.x; acc.y += wgt * v.y;
        acc.z += wgt * v.z; acc.w += wgt * v.w;
    }
    // reduce over the 4 m-subgroups (lanes xor 16, 32)
    #pragma unroll
    for (int m = 16; m <= 32; m <<= 1) {
        acc.x += __shfl_xor(acc.x, m); acc.y += __shfl_xor(acc.y, m);
        acc.z += __shfl_xor(acc.z, m); acc.w += __shfl_xor(acc.w, m);
    }
    // lorentz inner: minus sign on o==0 (lane c==0, component .x)
    float s = acc.x * acc.x + acc.y * acc.y + acc.z * acc.z + acc.w * acc.w;
    if (c == 0) s -= 2.0f * acc.x * acc.x;
    #pragma unroll
    for (int m = 1; m <= 8; m <<= 1) s += __shfl_xor(s, m);
    float den = sqrtf(fmaxf(fabsf(s), 1e-8f));
    if (g == 0) {
        float4 rr = {acc.x / den, acc.y / den, acc.z / den, acc.w / den};
        ((float4*)out)[(size_t)n * 16 + c] = rr;
    }
}

// ---------------------------------------------------------------- launch ---
extern "C" void kernel_launch(void* const* d_in, const int* in_sizes, int n_in,
                              void* d_out, int out_size, void* d_ws, size_t ws_size,
                              hipStream_t stream) {
    const float* x      = (const float*)d_in[0];  // (12000, 64) f32
    const int*   nei    = (const int*)  d_in[1];  // (12000, 32) int32
    const int*   mask   = (const int*)  d_in[2];  // (12000, 32) int32
    const float* kp     = (const float*)d_in[3];  // (8, 64) f32
    const float* W      = (const float*)d_in[4];  // (8, 64, 64) f32
    const float* b      = (const float*)d_in[5];  // (8, 64) f32
    const float* scales = (const float*)d_in[6];  // (8,) f32
    float*       out    = (float*)d_out;          // (12000, 64) f32

    // ws: F (N*D f32) ; Wpk (8192 bf16x8 = 128KB)
    const size_t needed = (size_t)(NPTS * DD) * sizeof(float) + 8192 * 16;
    if (ws_size < needed) return;
    float*  F   = (float*)d_ws;
    bf16x8* Wpk = (bf16x8*)(F + (size_t)NPTS * DD);

    packW_kernel<<<8, 512, 0, stream>>>(W, Wpk);
    passA_kernel<<<NPTS / 16, 512, 0, stream>>>(x, kp, scales, Wpk, b, F);
    passB_kernel<<<NPTS / 4, 256, 0, stream>>>(F, nei, mask, out);
}

// Round 18
// 31.555 us; speedup vs baseline: 4.8129x; 4.8129x over previous
//
#include <hip/hip_runtime.h>
#include <math.h>

// Problem constants: N=12000, NEI=32, K=8, D=64
#define NPTS 12000
#define NNEI 32
#define KK   8
#define DD   64

// Round 18 (= R17 structure MINUS the __threadfence calls):
//  - R17's per-wave __threadfence() emitted L2-writeback per wave (6000
//    waves -> ~123us of serialized fence cost, passA 140us). Removed.
//  - Keep R17's structural wins: kmF/esA handoff eliminated (passA
//    recomputes km row + exp(scales) per block -- measured free, and it
//    drops VGPR 88 -> 60, occupancy 19% -> ~33%, up to 4 blocks/CU at
//    LDS 37888).
//  - 2 cross-kernel handoffs (Wpk, F) instead of R12's 3.
//  - Perf core unchanged from R12 (best proven 30.7us): packW fragments,
//    750x512 balanced passA (fp32 dot -> exact u=1/z softmax, split-bf16
//    MFMA hh+hl+lh, stride-68 xtr), coalesced passB.

typedef __bf16 bf16x8 __attribute__((ext_vector_type(8)));
typedef float  f32x4  __attribute__((ext_vector_type(4)));

#define MFMA16(A, B, C) __builtin_amdgcn_mfma_f32_16x16x32_bf16((A), (B), (C), 0, 0, 0)

__device__ __forceinline__ void pack8(float4 u, float4 v, bf16x8& h, bf16x8& l) {
    float a[8] = {u.x, u.y, u.z, u.w, v.x, v.y, v.z, v.w};
    #pragma unroll
    for (int i = 0; i < 8; ++i) {
        __bf16 hh = (__bf16)a[i];
        h[i] = hh;
        l[i] = (__bf16)(a[i] - (float)hh);
    }
}

__device__ __forceinline__ float dot4(float4 a, float4 b) {
    return a.x * b.x + a.y * b.y + a.z * b.z + a.w * b.w;
}

// ---------------------------------------------------------------- packW ----
// 8 blocks x 512: W -> split-bf16 fragments in fragment order.
__launch_bounds__(512)
__global__ void packW_kernel(const float* __restrict__ W,
                             bf16x8* __restrict__ Wpk) {
    const int t    = threadIdx.x;
    const int id   = blockIdx.x * 512 + t;   // 0..4095
    const int lane = id & 63;
    const int ks   = (id >> 6) & 1;
    const int nt   = (id >> 7) & 3;
    const int k    = id >> 9;
    const int c    = lane & 15;
    const int g    = lane >> 4;

    const float* wr = W + ((size_t)k * DD + nt * 16 + c) * DD + ks * 32 + g * 8;
    bf16x8 h, l;
    pack8(*(const float4*)wr, *(const float4*)(wr + 4), h, l);
    const size_t base = ((((size_t)k * 4 + nt) * 2 + ks) * 2) * 64 + lane;
    Wpk[base]      = h;   // hi plane
    Wpk[base + 64] = l;   // lo plane
}

// ---------------------------------------------------------------- pass A ---
__launch_bounds__(512)
__global__ void passA_kernel(const float* __restrict__ x,
                             const float* __restrict__ kp,
                             const float* __restrict__ scales,
                             const bf16x8* __restrict__ Wpk,
                             const float* __restrict__ b,
                             float* __restrict__ F) {
    __shared__ float xtr[KK][16][68];   // stride 68: write/read both 2-way (free)
    __shared__ float kmL[KK][DD];       // per-wave km row (wave-private)
    __shared__ float disl[16][12];      // u = 1/z per (point, k)

    const int t    = threadIdx.x;
    const int k    = t >> 6;            // wave index == kernel index
    const int lane = t & 63;
    const int c    = lane & 15;
    const int g    = lane >> 4;
    const int pbase = blockIdx.x * 16;

    // ---- km row for this wave's k (recomputed per block; ~free) ----
    {
        float spv = (lane == 0) ? 0.f : kp[k * DD + lane];   // kp[:,0]==0
        float ss = spv * spv;
        #pragma unroll
        for (int off = 32; off > 0; off >>= 1) ss += __shfl_xor(ss, off);
        float nrm = sqrtf(fmaxf(ss, 1e-8f));
        float e  = __expf(nrm);
        float ei = 1.0f / e;
        kmL[k][lane] = (lane == 0) ? 0.5f * (e + ei)
                                   : -(0.5f * (e - ei) / nrm) * spv;
    }
    const float es = __expf(scales[k]);

    // ---- prologue: coalesced Wpk fragment loads ----
    bf16x8 Wh[4][2], Wl[4][2];
    #pragma unroll
    for (int nt = 0; nt < 4; ++nt)
        #pragma unroll
        for (int ks = 0; ks < 2; ++ks) {
            const size_t base = ((((size_t)k * 4 + nt) * 2 + ks) * 2) * 64 + lane;
            Wh[nt][ks] = Wpk[base];
            Wl[nt][ks] = Wpk[base + 64];
        }
    float bnt[4];
    #pragma unroll
    for (int nt = 0; nt < 4; ++nt) bnt[nt] = b[k * DD + nt * 16 + c];

    // ---- x row chunks (16 floats, kept live for dot + pack) ----
    float4 u0, u1, u2, u3;
    {
        const float* xr = x + (size_t)(pbase + c) * DD + g * 8;
        u0 = *(const float4*)(xr +  0);
        u1 = *(const float4*)(xr +  4);
        u2 = *(const float4*)(xr + 32);
        u3 = *(const float4*)(xr + 36);
    }

    // ---- inner product <x_row, km_k>; softmax numerator u = 1/z (exact) ----
    {
        const float4* km4 = (const float4*)&kmL[k][0];
        float ip = dot4(u0, km4[g * 2 + 0]) + dot4(u1, km4[g * 2 + 1])
                 + dot4(u2, km4[g * 2 + 8]) + dot4(u3, km4[g * 2 + 9]);
        ip += __shfl_xor(ip, 16);
        ip += __shfl_xor(ip, 32);   // all 4 g-groups summed; lanes with same c agree
        if (g == 0) {
            float nc = fmaxf(ip, 1.0f + 1e-7f);
            // exp(-arccosh(nc)) = 1 / (nc + sqrt(nc^2 - 1))  -- exact
            disl[c][k] = 1.0f / (nc + sqrtf(nc * nc - 1.0f));
        }
    }

    // ---- A fragments ----
    bf16x8 Ah[2], Al[2];
    pack8(u0, u1, Ah[0], Al[0]);
    pack8(u2, u3, Ah[1], Al[1]);

    // ---- MFMAs: Y only (24) ----
    f32x4 accY[4];
    #pragma unroll
    for (int nt = 0; nt < 4; ++nt) accY[nt] = (f32x4){0.f, 0.f, 0.f, 0.f};
    #pragma unroll
    for (int ks = 0; ks < 2; ++ks)
        #pragma unroll
        for (int nt = 0; nt < 4; ++nt) {
            accY[nt] = MFMA16(Ah[ks], Wh[nt][ks], accY[nt]);
            accY[nt] = MFMA16(Ah[ks], Wl[nt][ks], accY[nt]);
            accY[nt] = MFMA16(Al[ks], Wh[nt][ks], accY[nt]);
        }

    // ---- epilogue: per-point stats (C layout: row p=g*4+rr, col o=nt*16+c) ----
    float yv[4][4], sall[4];
    #pragma unroll
    for (int rr = 0; rr < 4; ++rr) {
        float s = 0.f;
        #pragma unroll
        for (int nt = 0; nt < 4; ++nt) {
            float y = accY[nt][rr] + bnt[nt];
            yv[nt][rr] = y;
            s += y * y;
        }
        sall[rr] = s;
    }
    #pragma unroll
    for (int m = 1; m <= 8; m <<= 1)
        #pragma unroll
        for (int rr = 0; rr < 4; ++rr) sall[rr] += __shfl_xor(sall[rr], m);
    float y0[4];
    #pragma unroll
    for (int rr = 0; rr < 4; ++rr) y0[rr] = __shfl(yv[0][rr], lane & 48);

    #pragma unroll
    for (int rr = 0; rr < 4; ++rr) {
        const int p = g * 4 + rr;
        float nar2 = fmaxf(sall[rr] - y0[rr] * y0[rr], 1e-8f);
        float time = es / (1.0f + __expf(-y0[rr])) + 1.0001f;
        float s3   = sqrtf((time * time - 1.0f) / nar2);
        #pragma unroll
        for (int nt = 0; nt < 4; ++nt) {
            float v = yv[nt][rr] * s3;
            if (nt == 0 && c == 0) v = time;
            xtr[k][p][nt * 16 + c] = v;
        }
    }
    __syncthreads();

    // ---- combine: wave k handles points {2k, 2k+1} ----
    #pragma unroll
    for (int pi = 0; pi < 2; ++pi) {
        const int p = k * 2 + pi;
        float uk[KK];
        float sum = 0.f;
        #pragma unroll
        for (int q = 0; q < KK; ++q) { uk[q] = disl[p][q]; sum += uk[q]; }
        float inv = 1.0f / sum;
        float agg = 0.f;
        #pragma unroll
        for (int q = 0; q < KK; ++q) agg += uk[q] * inv * xtr[q][p][lane];

        float vv = (lane == 0) ? -agg * agg : agg * agg;
        #pragma unroll
        for (int m = 32; m > 0; m >>= 1) vv += __shfl_xor(vv, m);
        float den = sqrtf(fmaxf(fabsf(vv), 1e-8f));
        F[(size_t)(pbase + p) * DD + lane] = agg / den;
    }
}

// ---------------------------------------------------------------- pass B ---
__launch_bounds__(256)
__global__ void passB_kernel(const float* __restrict__ F,
                             const int* __restrict__ nei,
                             const int* __restrict__ mask,
                             float* __restrict__ out) {
    const int t    = threadIdx.x;
    const int wave = t >> 6;
    const int lane = t & 63;
    const int c    = lane & 15;   // col quad: o = 4c..4c+3
    const int g    = lane >> 4;   // m sub-index
    const int n    = blockIdx.x * 4 + wave;

    // one coalesced 256B fetch per wave: lanes 0..31 nei row, 32..63 mask row
    int vsrc;
    if (lane < 32) vsrc = nei[n * NNEI + lane];
    else           vsrc = mask[n * NNEI + (lane - 32)];

    const float4* F4 = (const float4*)F;
    float4 acc = {0.f, 0.f, 0.f, 0.f};
    #pragma unroll
    for (int mq = 0; mq < 8; ++mq) {
        int   m   = mq * 4 + g;
        int   j   = __shfl(vsrc, m);
        float wgt = (float)__shfl(vsrc, 32 + m) + 1e-4f;
        float4 v  = F4[(size_t)j * 16 + c];
        acc.x += wgt * v.x; acc.y += wgt * v.y;
        acc.z += wgt * v.z; acc.w += wgt * v.w;
    }
    // reduce over the 4 m-subgroups (lanes xor 16, 32)
    #pragma unroll
    for (int m = 16; m <= 32; m <<= 1) {
        acc.x += __shfl_xor(acc.x, m); acc.y += __shfl_xor(acc.y, m);
        acc.z += __shfl_xor(acc.z, m); acc.w += __shfl_xor(acc.w, m);
    }
    // lorentz inner: minus sign on o==0 (lane c==0, component .x)
    float s = acc.x * acc.x + acc.y * acc.y + acc.z * acc.z + acc.w * acc.w;
    if (c == 0) s -= 2.0f * acc.x * acc.x;
    #pragma unroll
    for (int m = 1; m <= 8; m <<= 1) s += __shfl_xor(s, m);
    float den = sqrtf(fmaxf(fabsf(s), 1e-8f));
    if (g == 0) {
        float4 rr = {acc.x / den, acc.y / den, acc.z / den, acc.w / den};
        ((float4*)out)[(size_t)n * 16 + c] = rr;
    }
}

// ---------------------------------------------------------------- launch ---
extern "C" void kernel_launch(void* const* d_in, const int* in_sizes, int n_in,
                              void* d_out, int out_size, void* d_ws, size_t ws_size,
                              hipStream_t stream) {
    const float* x      = (const float*)d_in[0];  // (12000, 64) f32
    const int*   nei    = (const int*)  d_in[1];  // (12000, 32) int32
    const int*   mask   = (const int*)  d_in[2];  // (12000, 32) int32
    const float* kp     = (const float*)d_in[3];  // (8, 64) f32
    const float* W      = (const float*)d_in[4];  // (8, 64, 64) f32
    const float* b      = (const float*)d_in[5];  // (8, 64) f32
    const float* scales = (const float*)d_in[6];  // (8,) f32
    float*       out    = (float*)d_out;          // (12000, 64) f32

    // ws: F (N*D f32) ; Wpk (8192 bf16x8 = 128KB)
    const size_t needed = (size_t)(NPTS * DD) * sizeof(float) + 8192 * 16;
    if (ws_size < needed) return;
    float*  F   = (float*)d_ws;
    bf16x8* Wpk = (bf16x8*)(F + (size_t)NPTS * DD);

    packW_kernel<<<8, 512, 0, stream>>>(W, Wpk);
    passA_kernel<<<NPTS / 16, 512, 0, stream>>>(x, kp, scales, Wpk, b, F);
    passB_kernel<<<NPTS / 4, 256, 0, stream>>>(F, nei, mask, out);
}

// Round 19
// 31.163 us; speedup vs baseline: 4.8735x; 1.0126x over previous
//
#include <hip/hip_runtime.h>
#include <math.h>

// Problem constants: N=12000, NEI=32, K=8, D=64
#define NPTS 12000
#define NNEI 32
#define KK   8
#define DD   64

// FINAL (round 19 = R18 + b-via-shfl prologue fix).
// Session ledger: 83.1 -> 31 us via: 32x algorithmic reduction (per-point
// factorization), MFMA w/ split-bf16 fp32 emulation, balanced 750-block
// grid, W pre-pack to fragment order, prologue compute moved to producer,
// exact softmax algebra (exp(-arccosh(z)) = 1/(z+sqrt(z^2-1))), coalesced
// passB (wave-wide nei/mask fetch + shfl distribution).
// Floor analysis: passA ~16us = per-block serial chain + 96MB L2 Wpk
// re-reads (~3us floor) at ~3 blocks/CU; passB ~3.5us (L2-bound gather);
// ~9us 3-node launch/gap overhead. All fusion routes failed fatally
// (R4 occupancy / R7 VGPR cap / R14 coop deadlock); fences mispriced (R17).
// R18 structure chosen over R12 (-0.9us) for the clean revalidation record.

typedef __bf16 bf16x8 __attribute__((ext_vector_type(8)));
typedef float  f32x4  __attribute__((ext_vector_type(4)));

#define MFMA16(A, B, C) __builtin_amdgcn_mfma_f32_16x16x32_bf16((A), (B), (C), 0, 0, 0)

__device__ __forceinline__ void pack8(float4 u, float4 v, bf16x8& h, bf16x8& l) {
    float a[8] = {u.x, u.y, u.z, u.w, v.x, v.y, v.z, v.w};
    #pragma unroll
    for (int i = 0; i < 8; ++i) {
        __bf16 hh = (__bf16)a[i];
        h[i] = hh;
        l[i] = (__bf16)(a[i] - (float)hh);
    }
}

__device__ __forceinline__ float dot4(float4 a, float4 b) {
    return a.x * b.x + a.y * b.y + a.z * b.z + a.w * b.w;
}

// ---------------------------------------------------------------- packW ----
// 8 blocks x 512: W -> split-bf16 fragments in fragment order.
__launch_bounds__(512)
__global__ void packW_kernel(const float* __restrict__ W,
                             bf16x8* __restrict__ Wpk) {
    const int t    = threadIdx.x;
    const int id   = blockIdx.x * 512 + t;   // 0..4095
    const int lane = id & 63;
    const int ks   = (id >> 6) & 1;
    const int nt   = (id >> 7) & 3;
    const int k    = id >> 9;
    const int c    = lane & 15;
    const int g    = lane >> 4;

    const float* wr = W + ((size_t)k * DD + nt * 16 + c) * DD + ks * 32 + g * 8;
    bf16x8 h, l;
    pack8(*(const float4*)wr, *(const float4*)(wr + 4), h, l);
    const size_t base = ((((size_t)k * 4 + nt) * 2 + ks) * 2) * 64 + lane;
    Wpk[base]      = h;   // hi plane
    Wpk[base + 64] = l;   // lo plane
}

// ---------------------------------------------------------------- pass A ---
__launch_bounds__(512)
__global__ void passA_kernel(const float* __restrict__ x,
                             const float* __restrict__ kp,
                             const float* __restrict__ scales,
                             const bf16x8* __restrict__ Wpk,
                             const float* __restrict__ b,
                             float* __restrict__ F) {
    __shared__ float xtr[KK][16][68];   // stride 68: write/read both 2-way (free)
    __shared__ float kmL[KK][DD];       // per-wave km row (wave-private)
    __shared__ float disl[16][12];      // u = 1/z per (point, k)

    const int t    = threadIdx.x;
    const int k    = t >> 6;            // wave index == kernel index
    const int lane = t & 63;
    const int c    = lane & 15;
    const int g    = lane >> 4;
    const int pbase = blockIdx.x * 16;

    // ---- km row for this wave's k (recomputed per block; ~free) ----
    {
        float spv = (lane == 0) ? 0.f : kp[k * DD + lane];   // kp[:,0]==0
        float ss = spv * spv;
        #pragma unroll
        for (int off = 32; off > 0; off >>= 1) ss += __shfl_xor(ss, off);
        float nrm = sqrtf(fmaxf(ss, 1e-8f));
        float e  = __expf(nrm);
        float ei = 1.0f / e;
        kmL[k][lane] = (lane == 0) ? 0.5f * (e + ei)
                                   : -(0.5f * (e - ei) / nrm) * spv;
    }
    const float es = __expf(scales[k]);

    // ---- b row: ONE coalesced load + shfl (was 4 uncoalesced loads) ----
    float bnt[4];
    {
        float bl = b[k * DD + lane];
        #pragma unroll
        for (int nt = 0; nt < 4; ++nt) bnt[nt] = __shfl(bl, nt * 16 + c);
    }

    // ---- prologue: coalesced Wpk fragment loads ----
    bf16x8 Wh[4][2], Wl[4][2];
    #pragma unroll
    for (int nt = 0; nt < 4; ++nt)
        #pragma unroll
        for (int ks = 0; ks < 2; ++ks) {
            const size_t base = ((((size_t)k * 4 + nt) * 2 + ks) * 2) * 64 + lane;
            Wh[nt][ks] = Wpk[base];
            Wl[nt][ks] = Wpk[base + 64];
        }

    // ---- x row chunks (16 floats, kept live for dot + pack) ----
    float4 u0, u1, u2, u3;
    {
        const float* xr = x + (size_t)(pbase + c) * DD + g * 8;
        u0 = *(const float4*)(xr +  0);
        u1 = *(const float4*)(xr +  4);
        u2 = *(const float4*)(xr + 32);
        u3 = *(const float4*)(xr + 36);
    }

    // ---- inner product <x_row, km_k>; softmax numerator u = 1/z (exact) ----
    {
        const float4* km4 = (const float4*)&kmL[k][0];
        float ip = dot4(u0, km4[g * 2 + 0]) + dot4(u1, km4[g * 2 + 1])
                 + dot4(u2, km4[g * 2 + 8]) + dot4(u3, km4[g * 2 + 9]);
        ip += __shfl_xor(ip, 16);
        ip += __shfl_xor(ip, 32);   // all 4 g-groups summed; lanes with same c agree
        if (g == 0) {
            float nc = fmaxf(ip, 1.0f + 1e-7f);
            // exp(-arccosh(nc)) = 1 / (nc + sqrt(nc^2 - 1))  -- exact
            disl[c][k] = 1.0f / (nc + sqrtf(nc * nc - 1.0f));
        }
    }

    // ---- A fragments ----
    bf16x8 Ah[2], Al[2];
    pack8(u0, u1, Ah[0], Al[0]);
    pack8(u2, u3, Ah[1], Al[1]);

    // ---- MFMAs: Y only (24) ----
    f32x4 accY[4];
    #pragma unroll
    for (int nt = 0; nt < 4; ++nt) accY[nt] = (f32x4){0.f, 0.f, 0.f, 0.f};
    #pragma unroll
    for (int ks = 0; ks < 2; ++ks)
        #pragma unroll
        for (int nt = 0; nt < 4; ++nt) {
            accY[nt] = MFMA16(Ah[ks], Wh[nt][ks], accY[nt]);
            accY[nt] = MFMA16(Ah[ks], Wl[nt][ks], accY[nt]);
            accY[nt] = MFMA16(Al[ks], Wh[nt][ks], accY[nt]);
        }

    // ---- epilogue: per-point stats (C layout: row p=g*4+rr, col o=nt*16+c) ----
    float yv[4][4], sall[4];
    #pragma unroll
    for (int rr = 0; rr < 4; ++rr) {
        float s = 0.f;
        #pragma unroll
        for (int nt = 0; nt < 4; ++nt) {
            float y = accY[nt][rr] + bnt[nt];
            yv[nt][rr] = y;
            s += y * y;
        }
        sall[rr] = s;
    }
    #pragma unroll
    for (int m = 1; m <= 8; m <<= 1)
        #pragma unroll
        for (int rr = 0; rr < 4; ++rr) sall[rr] += __shfl_xor(sall[rr], m);
    float y0[4];
    #pragma unroll
    for (int rr = 0; rr < 4; ++rr) y0[rr] = __shfl(yv[0][rr], lane & 48);

    #pragma unroll
    for (int rr = 0; rr < 4; ++rr) {
        const int p = g * 4 + rr;
        float nar2 = fmaxf(sall[rr] - y0[rr] * y0[rr], 1e-8f);
        float time = es / (1.0f + __expf(-y0[rr])) + 1.0001f;
        float s3   = sqrtf((time * time - 1.0f) / nar2);
        #pragma unroll
        for (int nt = 0; nt < 4; ++nt) {
            float v = yv[nt][rr] * s3;
            if (nt == 0 && c == 0) v = time;
            xtr[k][p][nt * 16 + c] = v;
        }
    }
    __syncthreads();

    // ---- combine: wave k handles points {2k, 2k+1} ----
    #pragma unroll
    for (int pi = 0; pi < 2; ++pi) {
        const int p = k * 2 + pi;
        float uk[KK];
        float sum = 0.f;
        #pragma unroll
        for (int q = 0; q < KK; ++q) { uk[q] = disl[p][q]; sum += uk[q]; }
        float inv = 1.0f / sum;
        float agg = 0.f;
        #pragma unroll
        for (int q = 0; q < KK; ++q) agg += uk[q] * inv * xtr[q][p][lane];

        float vv = (lane == 0) ? -agg * agg : agg * agg;
        #pragma unroll
        for (int m = 32; m > 0; m >>= 1) vv += __shfl_xor(vv, m);
        float den = sqrtf(fmaxf(fabsf(vv), 1e-8f));
        F[(size_t)(pbase + p) * DD + lane] = agg / den;
    }
}

// ---------------------------------------------------------------- pass B ---
__launch_bounds__(256)
__global__ void passB_kernel(const float* __restrict__ F,
                             const int* __restrict__ nei,
                             const int* __restrict__ mask,
                             float* __restrict__ out) {
    const int t    = threadIdx.x;
    const int wave = t >> 6;
    const int lane = t & 63;
    const int c    = lane & 15;   // col quad: o = 4c..4c+3
    const int g    = lane >> 4;   // m sub-index
    const int n    = blockIdx.x * 4 + wave;

    // one coalesced 256B fetch per wave: lanes 0..31 nei row, 32..63 mask row
    int vsrc;
    if (lane < 32) vsrc = nei[n * NNEI + lane];
    else           vsrc = mask[n * NNEI + (lane - 32)];

    const float4* F4 = (const float4*)F;
    float4 acc = {0.f, 0.f, 0.f, 0.f};
    #pragma unroll
    for (int mq = 0; mq < 8; ++mq) {
        int   m   = mq * 4 + g;
        int   j   = __shfl(vsrc, m);
        float wgt = (float)__shfl(vsrc, 32 + m) + 1e-4f;
        float4 v  = F4[(size_t)j * 16 + c];
        acc.x += wgt * v.x; acc.y += wgt * v.y;
        acc.z += wgt * v.z; acc.w += wgt * v.w;
    }
    // reduce over the 4 m-subgroups (lanes xor 16, 32)
    #pragma unroll
    for (int m = 16; m <= 32; m <<= 1) {
        acc.x += __shfl_xor(acc.x, m); acc.y += __shfl_xor(acc.y, m);
        acc.z += __shfl_xor(acc.z, m); acc.w += __shfl_xor(acc.w, m);
    }
    // lorentz inner: minus sign on o==0 (lane c==0, component .x)
    float s = acc.x * acc.x + acc.y * acc.y + acc.z * acc.z + acc.w * acc.w;
    if (c == 0) s -= 2.0f * acc.x * acc.x;
    #pragma unroll
    for (int m = 1; m <= 8; m <<= 1) s += __shfl_xor(s, m);
    float den = sqrtf(fmaxf(fabsf(s), 1e-8f));
    if (g == 0) {
        float4 rr = {acc.x / den, acc.y / den, acc.z / den, acc.w / den};
        ((float4*)out)[(size_t)n * 16 + c] = rr;
    }
}

// ---------------------------------------------------------------- launch ---
extern "C" void kernel_launch(void* const* d_in, const int* in_sizes, int n_in,
                              void* d_out, int out_size, void* d_ws, size_t ws_size,
                              hipStream_t stream) {
    const float* x      = (const float*)d_in[0];  // (12000, 64) f32
    const int*   nei    = (const int*)  d_in[1];  // (12000, 32) int32
    const int*   mask   = (const int*)  d_in[2];  // (12000, 32) int32
    const float* kp     = (const float*)d_in[3];  // (8, 64) f32
    const float* W      = (const float*)d_in[4];  // (8, 64, 64) f32
    const float* b      = (const float*)d_in[5];  // (8, 64) f32
    const float* scales = (const float*)d_in[6];  // (8,) f32
    float*       out    = (float*)d_out;          // (12000, 64) f32

    // ws: F (N*D f32) ; Wpk (8192 bf16x8 = 128KB)
    const size_t needed = (size_t)(NPTS * DD) * sizeof(float) + 8192 * 16;
    if (ws_size < needed) return;
    float*  F   = (float*)d_ws;
    bf16x8* Wpk = (bf16x8*)(F + (size_t)NPTS * DD);

    packW_kernel<<<8, 512, 0, stream>>>(W, Wpk);
    passA_kernel<<<NPTS / 16, 512, 0, stream>>>(x, kp, scales, Wpk, b, F);
    passB_kernel<<<NPTS / 4, 256, 0, stream>>>(F, nei, mask, out);
}